// Round 4
// baseline (504.444 us; speedup 1.0000x reference)
//
#include <hip/hip_runtime.h>

#define B_ 8
#define C_ 32
#define H_ 512
#define W_ 512
#define HW_ (H_ * W_)
#define BN_EPS 1e-5f
#define NBLK 512   // 2/CU x 256 CU -> all blocks co-resident (see barrier note)

typedef float f4v __attribute__((ext_vector_type(4)));

// ws layout:
//   float part[NBLK][8]   @ byte 0      (written by every block -> no zeroing)
//   unsigned counter      @ byte 16384  (zeroed by 4-byte memset each launch)

__global__ __launch_bounds__(256, 2) void fourdir_fused(
    const float* __restrict__ x,
    const float* __restrict__ w,
    float* __restrict__ y,
    float* __restrict__ part,
    unsigned* __restrict__ counter,
    const float* __restrict__ gamma,
    const float* __restrict__ beta)
{
    // Weight LDS: wl4[d][c] = float4 over o (d: 0=ne,1=nw,2=se,3=sw,4=center)
    __shared__ f4v wl4[5][C_];
    const int t = threadIdx.x;
    {
        float* wl = (float*)wl4;
        for (int idx = t; idx < 4 * 4 * C_; idx += 256) {
            int o  = idx & 3;
            int dc = idx >> 2;
            wl[idx] = w[o * (4 * C_) + dc];
        }
    }
    __syncthreads();
    if (t < 4 * C_) {
        float* wl = (float*)wl4;
        wl[512 + t] = -(wl[t] + wl[128 + t] + wl[256 + t] + wl[384 + t]);
    }
    __syncthreads();

    // XCD-aware swizzle: workgroup n -> XCD n%8; XCD k owns all 64 tiles of
    // batch k (B_ == 8 XCDs) so vertical halo rows share the XCD-local L2.
    const int n    = (int)blockIdx.x;
    const int tile = ((n & 7) << 6) | (n >> 3);
    const int cx   = tile & 1;          // 2 column halves
    const int iy   = (tile >> 1) & 31;  // 32 row-tiles
    const int b    = tile >> 6;         // batch == XCD id
    const int bid  = n;

    // Wave-contiguous tiling: wave = 4 rows x 256 cols; lane covers 4 cols.
    const int lane = t & 63;
    const int wv   = t >> 6;
    const int c0 = cx << 8;
    const int i0 = (iy << 4) + (wv << 2);
    const int j  = c0 + (lane << 2);
    const float* xb = x + (size_t)b * C_ * HW_;

    const bool jm = (c0 > 0);
    const bool jp = (c0 + 256 < W_);
    const bool tv = (i0 > 0);
    const bool bv = (i0 + 4 < H_);
    const bool edgeL = (lane == 0);
    const bool edgeR = (lane == 63);

    int off[6];
    {
        const int rows[6] = { tv ? i0 - 1 : 0, i0, i0 + 1, i0 + 2, i0 + 3,
                              bv ? i0 + 4 : 0 };
#pragma unroll
        for (int k = 0; k < 6; ++k) off[k] = rows[k] * W_ + j;
    }

    f4v acc[4][4];
#pragma unroll
    for (int p = 0; p < 4; ++p)
#pragma unroll
        for (int q = 0; q < 4; ++q) acc[p][q] = f4v{0.f, 0.f, 0.f, 0.f};

    auto LOADCH = [&](int c, f4v (&vr)[6], float (&le)[6], float (&re)[6]) {
        const float* xc = xb + (size_t)c * HW_;
#pragma unroll
        for (int k = 0; k < 6; ++k) vr[k] = *(const f4v*)(xc + off[k]);
#pragma unroll
        for (int k = 0; k < 6; ++k) {
            float l = 0.f, r = 0.f;
            if (edgeL && jm) l = xc[off[k] - 1];
            if (edgeR && jp) r = xc[off[k] + 4];
            le[k] = l;
            re[k] = r;
        }
        if (!tv) { vr[0] = f4v{0.f,0.f,0.f,0.f}; le[0] = 0.f; re[0] = 0.f; }
        if (!bv) { vr[5] = f4v{0.f,0.f,0.f,0.f}; le[5] = 0.f; re[5] = 0.f; }
    };

    auto COMPCH = [&](int c, const f4v (&vr)[6],
                      const float (&le)[6], const float (&re)[6]) {
        const f4v wne = wl4[0][c];
        const f4v wnw = wl4[1][c];
        const f4v wse = wl4[2][c];
        const f4v wsw = wl4[3][c];
        const f4v wct = wl4[4][c];

        float lf[6], rt[6];
#pragma unroll
        for (int k = 0; k < 6; ++k) {
            const float l = __shfl_up(vr[k][3], 1, 64);
            const float r = __shfl_down(vr[k][0], 1, 64);
            lf[k] = edgeL ? le[k] : l;
            rt[k] = edgeR ? re[k] : r;
        }

#pragma unroll
        for (int p = 0; p < 4; ++p) {
#pragma unroll
            for (int q = 0; q < 4; ++q) {
                const float ne = (q < 3) ? vr[p][q + 1]     : rt[p];
                const float nw = (q > 0) ? vr[p][q - 1]     : lf[p];
                const float se = (q < 3) ? vr[p + 2][q + 1] : rt[p + 2];
                const float sw = (q > 0) ? vr[p + 2][q - 1] : lf[p + 2];
                const float ct = vr[p + 1][q];
                acc[p][q] += wne * ne + wnw * nw + wse * se + wsw * sw + wct * ct;
            }
        }
    };

    // Software-pipelined channel loop.
    f4v vrA[6], vrB[6];
    float leA[6], reA[6], leB[6], reB[6];

    LOADCH(0, vrA, leA, reA);
#pragma unroll 1
    for (int cc = 0; cc < C_ - 2; cc += 2) {
        LOADCH(cc + 1, vrB, leB, reB);
        COMPCH(cc, vrA, leA, reA);
        LOADCH(cc + 2, vrA, leA, reA);
        COMPCH(cc + 1, vrB, leB, reB);
    }
    LOADCH(C_ - 1, vrB, leB, reB);
    COMPCH(C_ - 2, vrA, leA, reA);
    COMPCH(C_ - 1, vrB, leB, reB);

    // ---- per-block partial sums (sum / sumsq per output channel) ----
    f4v s0 = f4v{0.f,0.f,0.f,0.f}, s1 = f4v{0.f,0.f,0.f,0.f};
#pragma unroll
    for (int p = 0; p < 4; ++p)
#pragma unroll
        for (int q = 0; q < 4; ++q) {
            s0 += acc[p][q];
            s1 += acc[p][q] * acc[p][q];
        }

    float vals[8] = { s0[0], s0[1], s0[2], s0[3], s1[0], s1[1], s1[2], s1[3] };
#pragma unroll
    for (int k = 0; k < 8; ++k) {
        float v = vals[k];
#pragma unroll
        for (int o = 32; o >= 1; o >>= 1) v += __shfl_xor(v, o, 64);
        vals[k] = v;
    }

    __shared__ float red[4][8];
    if (lane == 0) {
#pragma unroll
        for (int k = 0; k < 8; ++k) red[wv][k] = vals[k];
    }
    __syncthreads();
    if (t < 8) {
        part[bid * 8 + t] = red[0][t] + red[1][t] + red[2][t] + red[3][t];
    }

    // ---- manual grid barrier: release partials, arrive, spin ----
    __threadfence();        // device-scope release of this thread's stores
    __syncthreads();        // all part-stores + fences happen-before t0's arrive
    if (t == 0) {
        __hip_atomic_fetch_add(counter, 1u, __ATOMIC_ACQ_REL,
                               __HIP_MEMORY_SCOPE_AGENT);
        // Bounded spin: all 512 blocks are co-resident (2/CU by launch
        // bounds), so this always completes; the bound turns any surprise
        // into a visible failure instead of a hang.
        int guard = 0;
        while (__hip_atomic_load(counter, __ATOMIC_ACQUIRE,
                                 __HIP_MEMORY_SCOPE_AGENT) < (unsigned)NBLK &&
               ++guard < (1 << 21)) {
            __builtin_amdgcn_s_sleep(8);
        }
    }
    __syncthreads();

    // ---- global reduce of 512x8 partials (each block, redundantly) ----
    float p8 = 0.f;
    const int k8 = t & 7;
#pragma unroll 4
    for (int ib = (t >> 3); ib < NBLK; ib += 32) p8 += part[ib * 8 + k8];

    __shared__ float redf[256];
    __shared__ float tot[8];
    redf[t] = p8;
    __syncthreads();
    if (t < 64) {
        float v = redf[t] + redf[t + 64] + redf[t + 128] + redf[t + 192];
        v += __shfl_xor(v, 8, 64);
        v += __shfl_xor(v, 16, 64);
        v += __shfl_xor(v, 32, 64);
        if (t < 8) tot[t] = v;
    }
    __syncthreads();

    // ---- BN scale/shift, apply in-register, single y write ----
    const float nn = (float)((size_t)B_ * HW_);
    f4v scale, shift;
#pragma unroll
    for (int o = 0; o < 4; ++o) {
        const float mean = tot[o] / nn;
        const float var  = tot[4 + o] / nn - mean * mean;
        const float sc   = rsqrtf(var + BN_EPS) * gamma[o];
        scale[o] = sc;
        shift[o] = beta[o] - mean * sc;
    }

#pragma unroll
    for (int p = 0; p < 4; ++p)
#pragma unroll
        for (int q = 0; q < 4; ++q)
            acc[p][q] = acc[p][q] * scale + shift;

#pragma unroll
    for (int p = 0; p < 4; ++p) {
        const size_t base = (size_t)(i0 + p) * W_ + j;
#pragma unroll
        for (int o = 0; o < 4; ++o) {
            f4v st = { acc[p][0][o], acc[p][1][o], acc[p][2][o], acc[p][3][o] };
            *(f4v*)(y + ((size_t)(b * 4 + o)) * HW_ + base) = st;
        }
    }
}

extern "C" void kernel_launch(void* const* d_in, const int* in_sizes, int n_in,
                              void* d_out, int out_size, void* d_ws, size_t ws_size,
                              hipStream_t stream) {
    const float* x     = (const float*)d_in[0];
    const float* w     = (const float*)d_in[1];
    const float* gamma = (const float*)d_in[2];
    const float* beta  = (const float*)d_in[3];
    float* out  = (float*)d_out;
    float* part = (float*)d_ws;
    unsigned* counter = (unsigned*)((char*)d_ws + 16384);

    // ws is poisoned 0xAA before every launch — zero only the 4-byte counter
    // (part[] slots are all overwritten every launch).
    hipMemsetAsync(counter, 0, sizeof(unsigned), stream);

    fourdir_fused<<<dim3(NBLK), 256, 0, stream>>>(x, w, out, part, counter,
                                                  gamma, beta);
}

// Round 5
// 384.809 us; speedup vs baseline: 1.3109x; 1.3109x over previous
//
#include <hip/hip_runtime.h>

#define B_ 8
#define C_ 32
#define H_ 512
#define W_ 512
#define HW_ (H_ * W_)
#define BN_EPS 1e-5f
#define NBLK 512

typedef float f4v __attribute__((ext_vector_type(4)));

// ws layout: float part[NBLK][8] = per-block {sum[o=0..3], sumsq[o=0..3]}.
// Every slot is written by its block every launch -> no zeroing needed
// despite the harness's 0xAA workspace poison. No atomics, no memset.

__global__ __launch_bounds__(256, 2) void fourdir_compute(
    const float* __restrict__ x,
    const float* __restrict__ w,
    float* __restrict__ y,
    float* __restrict__ part)
{
    // Weight LDS: wl4[d][c] = float4 over o (d: 0=ne,1=nw,2=se,3=sw,4=center)
    __shared__ f4v wl4[5][C_];
    const int t = threadIdx.x;
    {
        float* wl = (float*)wl4;
        for (int idx = t; idx < 4 * 4 * C_; idx += 256) {
            int o  = idx & 3;
            int dc = idx >> 2;
            wl[idx] = w[o * (4 * C_) + dc];
        }
    }
    __syncthreads();
    if (t < 4 * C_) {
        float* wl = (float*)wl4;
        wl[512 + t] = -(wl[t] + wl[128 + t] + wl[256 + t] + wl[384 + t]);
    }
    __syncthreads();

    // XCD-aware swizzle: workgroup n -> XCD n%8; XCD k owns all 64 tiles of
    // batch k (B_ == 8 XCDs) so vertical halo rows share the XCD-local L2.
    const int n    = (int)blockIdx.x;
    const int tile = ((n & 7) << 6) | (n >> 3);
    const int cx   = tile & 1;          // 2 column halves
    const int iy   = (tile >> 1) & 31;  // 32 row-tiles
    const int b    = tile >> 6;         // batch == XCD id

    // Wave-contiguous tiling: wave = 4 rows x 256 cols; lane covers 4 cols.
    // Every dwordx4 is a contiguous 1024B wave transaction.
    const int lane = t & 63;
    const int wv   = t >> 6;
    const int c0 = cx << 8;
    const int i0 = (iy << 4) + (wv << 2);
    const int j  = c0 + (lane << 2);
    const float* xb = x + (size_t)b * C_ * HW_;

    const bool jm = (c0 > 0);
    const bool jp = (c0 + 256 < W_);
    const bool tv = (i0 > 0);
    const bool bv = (i0 + 4 < H_);
    const bool edgeL = (lane == 0);
    const bool edgeR = (lane == 63);

    int off[6];
    {
        const int rows[6] = { tv ? i0 - 1 : 0, i0, i0 + 1, i0 + 2, i0 + 3,
                              bv ? i0 + 4 : 0 };
#pragma unroll
        for (int k = 0; k < 6; ++k) off[k] = rows[k] * W_ + j;
    }

    f4v acc[4][4];
#pragma unroll
    for (int p = 0; p < 4; ++p)
#pragma unroll
        for (int q = 0; q < 4; ++q) acc[p][q] = f4v{0.f, 0.f, 0.f, 0.f};

    auto LOADCH = [&](int c, f4v (&vr)[6], float (&le)[6], float (&re)[6]) {
        const float* xc = xb + (size_t)c * HW_;
#pragma unroll
        for (int k = 0; k < 6; ++k) vr[k] = *(const f4v*)(xc + off[k]);
#pragma unroll
        for (int k = 0; k < 6; ++k) {
            float l = 0.f, r = 0.f;
            if (edgeL && jm) l = xc[off[k] - 1];   // 1-lane masked load
            if (edgeR && jp) r = xc[off[k] + 4];   // 1-lane masked load
            le[k] = l;
            re[k] = r;
        }
        if (!tv) { vr[0] = f4v{0.f,0.f,0.f,0.f}; le[0] = 0.f; re[0] = 0.f; }
        if (!bv) { vr[5] = f4v{0.f,0.f,0.f,0.f}; le[5] = 0.f; re[5] = 0.f; }
    };

    auto COMPCH = [&](int c, const f4v (&vr)[6],
                      const float (&le)[6], const float (&re)[6]) {
        const f4v wne = wl4[0][c];
        const f4v wnw = wl4[1][c];
        const f4v wse = wl4[2][c];
        const f4v wsw = wl4[3][c];
        const f4v wct = wl4[4][c];

        float lf[6], rt[6];
#pragma unroll
        for (int k = 0; k < 6; ++k) {
            const float l = __shfl_up(vr[k][3], 1, 64);    // lane-1's col j-1
            const float r = __shfl_down(vr[k][0], 1, 64);  // lane+1's col j+4
            lf[k] = edgeL ? le[k] : l;
            rt[k] = edgeR ? re[k] : r;
        }

#pragma unroll
        for (int p = 0; p < 4; ++p) {
#pragma unroll
            for (int q = 0; q < 4; ++q) {
                const float ne = (q < 3) ? vr[p][q + 1]     : rt[p];
                const float nw = (q > 0) ? vr[p][q - 1]     : lf[p];
                const float se = (q < 3) ? vr[p + 2][q + 1] : rt[p + 2];
                const float sw = (q > 0) ? vr[p + 2][q - 1] : lf[p + 2];
                const float ct = vr[p + 1][q];
                acc[p][q] += wne * ne + wnw * nw + wse * se + wsw * sw + wct * ct;
            }
        }
    };

    // Software-pipelined channel loop: loads for c+1 in flight during compute of c.
    f4v vrA[6], vrB[6];
    float leA[6], reA[6], leB[6], reB[6];

    LOADCH(0, vrA, leA, reA);
#pragma unroll 1
    for (int cc = 0; cc < C_ - 2; cc += 2) {
        LOADCH(cc + 1, vrB, leB, reB);
        COMPCH(cc, vrA, leA, reA);
        LOADCH(cc + 2, vrA, leA, reA);
        COMPCH(cc + 1, vrB, leB, reB);
    }
    LOADCH(C_ - 1, vrB, leB, reB);
    COMPCH(C_ - 2, vrA, leA, reA);
    COMPCH(C_ - 1, vrB, leB, reB);

    // Write y = [B][4][H][W]; each wave's store is 1024B contiguous.
#pragma unroll
    for (int p = 0; p < 4; ++p) {
        const size_t base = (size_t)(i0 + p) * W_ + j;
#pragma unroll
        for (int o = 0; o < 4; ++o) {
            f4v st = { acc[p][0][o], acc[p][1][o], acc[p][2][o], acc[p][3][o] };
            *(f4v*)(y + ((size_t)(b * 4 + o)) * HW_ + base) = st;
        }
    }

    // Block reduction of sum / sumsq per output channel -> plain store
    f4v s0 = f4v{0.f,0.f,0.f,0.f}, s1 = f4v{0.f,0.f,0.f,0.f};
#pragma unroll
    for (int p = 0; p < 4; ++p)
#pragma unroll
        for (int q = 0; q < 4; ++q) {
            s0 += acc[p][q];
            s1 += acc[p][q] * acc[p][q];
        }

    float vals[8] = { s0[0], s0[1], s0[2], s0[3], s1[0], s1[1], s1[2], s1[3] };
#pragma unroll
    for (int k = 0; k < 8; ++k) {
        float v = vals[k];
#pragma unroll
        for (int o = 32; o >= 1; o >>= 1) v += __shfl_xor(v, o, 64);
        vals[k] = v;
    }

    __shared__ float red[4][8];
    if (lane == 0) {
#pragma unroll
        for (int k = 0; k < 8; ++k) red[wv][k] = vals[k];
    }
    __syncthreads();
    if (t < 8) {
        part[n * 8 + t] = red[0][t] + red[1][t] + red[2][t] + red[3][t];
    }
}

__global__ __launch_bounds__(256) void bn_norm(
    float* __restrict__ y,
    const float* __restrict__ part,
    const float* __restrict__ gamma,
    const float* __restrict__ beta)
{
    const int t = threadIdx.x;

    // Redundant per-block reduction of part[512][8] (16KB, L2-hot).
    // Thread t sums channel (t&7) over blocks ib = (t>>3) + 32k; flat index
    // (ib*8 + (t&7)) == t + 256k -> fully coalesced 1KB wave reads.
    float p8 = 0.f;
#pragma unroll
    for (int k = 0; k < 16; ++k) p8 += part[t + 256 * k];

    __shared__ float redf[256];
    __shared__ float tot[8];
    redf[t] = p8;
    __syncthreads();
    if (t < 64) {
        float v = redf[t] + redf[t + 64] + redf[t + 128] + redf[t + 192];
        v += __shfl_xor(v, 8, 64);
        v += __shfl_xor(v, 16, 64);
        v += __shfl_xor(v, 32, 64);
        if (t < 8) tot[t] = v;
    }
    __syncthreads();

    // XCD-aware swizzle: 2048 blocks, 256/batch; XCD n%8 handles batch n%8
    // (which that XCD's fourdir blocks just wrote -> L2/L3 hits on re-read).
    const int n = (int)blockIdx.x;
    const int m = ((n & 7) << 8) | (n >> 3);   // bijective [0,2048)

    // Block covers 1024 consecutive float4s = 16KB, inside one (b,o) plane.
    const int o = (m >> 6) & 3;

    const float nn = (float)((size_t)B_ * HW_);
    const float mean  = tot[o] / nn;
    const float var   = tot[4 + o] / nn - mean * mean;
    const float scale = rsqrtf(var + BN_EPS) * gamma[o];
    const float shift = beta[o] - mean * scale;

    float* base = y + ((size_t)m * 1024 + t) * 4;
#pragma unroll
    for (int k = 0; k < 4; ++k) {
        f4v v = *(const f4v*)(base + (size_t)k * 256 * 4);
        v = v * scale + shift;
        *(f4v*)(base + (size_t)k * 256 * 4) = v;
    }
}

extern "C" void kernel_launch(void* const* d_in, const int* in_sizes, int n_in,
                              void* d_out, int out_size, void* d_ws, size_t ws_size,
                              hipStream_t stream) {
    const float* x     = (const float*)d_in[0];
    const float* w     = (const float*)d_in[1];
    const float* gamma = (const float*)d_in[2];
    const float* beta  = (const float*)d_in[3];
    float* out  = (float*)d_out;
    float* part = (float*)d_ws;

    fourdir_compute<<<dim3(NBLK), 256, 0, stream>>>(x, w, out, part);
    bn_norm<<<dim3(2048), 256, 0, stream>>>(out, part, gamma, beta);
}